// Round 4
// baseline (463.050 us; speedup 1.0000x reference)
//
#include <hip/hip_runtime.h>

#define N_NODES 10000
#define N_EDGES 640000
#define DD 128

typedef __attribute__((ext_vector_type(8))) short short8;
typedef __attribute__((ext_vector_type(8))) float f32x8;
typedef __attribute__((ext_vector_type(4))) float f32x4;
typedef __attribute__((ext_vector_type(2))) float f32x2;

// pack two fp32 -> (bf16(hi)<<16)|bf16(lo), truncating: one v_perm_b32
__device__ __forceinline__ unsigned pack_bf2(float lo, float hi) {
  return __builtin_amdgcn_perm(__float_as_uint(hi), __float_as_uint(lo), 0x07060302u);
}

// Stage W (128x128 fp32 row-major) into LDS as bf16 with per-row XOR swizzle
// on 16B chunks: chunk c (cols c*8..c*8+7) of row j at slot (j*16)|(c^(j&7)).
__device__ __forceinline__ void stage_w(const float* __restrict__ W,
                                        short8* lwr) {
  const int tid = threadIdx.x;
#pragma unroll
  for (int t = 0; t < 8; ++t) {
    int s = t * 256 + tid;                          // chunk id 0..2047
    f32x8 v = *(const f32x8*)(W + (size_t)s * 8);   // coalesced 32B
    short8 av;
    unsigned* au = (unsigned*)&av;
    au[0] = pack_bf2(v[0], v[1]);
    au[1] = pack_bf2(v[2], v[3]);
    au[2] = pack_bf2(v[4], v[5]);
    au[3] = pack_bf2(v[6], v[7]);
    int j = s >> 4;
    int c = s & 15;
    lwr[(j << 4) | (c ^ (j & 7))] = av;
  }
  __syncthreads();
}

// ---------------------------------------------------------------------------
// CSR build: zero -> histogram -> scan -> fill
// ---------------------------------------------------------------------------
__global__ __launch_bounds__(256) void k_zero(int* __restrict__ count) {
  const int i = blockIdx.x * 256 + threadIdx.x;
  if (i < N_NODES) count[i] = 0;
}

__global__ __launch_bounds__(256) void k_hist(const int* __restrict__ EI,
                                              int* __restrict__ count) {
  const int e = blockIdx.x * 256 + threadIdx.x;
  atomicAdd(&count[EI[2 * e]], 1);
}

__global__ __launch_bounds__(1024) void k_scan(const int* __restrict__ count,
                                               int* __restrict__ rowptr,
                                               int* __restrict__ cursor) {
  __shared__ int part[1024];
  const int tid = threadIdx.x;
  const int base = tid * 10;
  int local[10];
  int s = 0;
#pragma unroll
  for (int i = 0; i < 10; ++i) {
    const int idx = base + i;
    const int v = (idx < N_NODES) ? count[idx] : 0;
    local[i] = s;
    s += v;
  }
  part[tid] = s;
  __syncthreads();
  for (int off = 1; off < 1024; off <<= 1) {
    int v = 0;
    if (tid >= off) v = part[tid - off];
    __syncthreads();
    if (tid >= off) part[tid] += v;
    __syncthreads();
  }
  const int excl = (tid > 0) ? part[tid - 1] : 0;
#pragma unroll
  for (int i = 0; i < 10; ++i) {
    const int idx = base + i;
    if (idx < N_NODES) {
      const int r = excl + local[i];
      rowptr[idx] = r;
      cursor[idx] = r;
    }
  }
  if (tid == 1023) rowptr[N_NODES] = part[1023];
}

__global__ __launch_bounds__(256) void k_fill(const int* __restrict__ EI,
                                              int* __restrict__ cursor,
                                              int* __restrict__ col) {
  const int e = blockIdx.x * 256 + threadIdx.x;
  const int s = EI[2 * e];
  const int pos = atomicAdd(&cursor[s], 1);
  col[pos] = e;
}

// ---------------------------------------------------------------------------
// Big GEMM: Yp = Y @ W^T   (640000x128 @ 128x128), fp32 I/O, bf16 MFMA
// Per wave: 32 edges x 128 outs; block = 4 waves, 2 chunks/block.
// Y loads are non-temporal (never re-read) to preserve L3 for Yp.
// ---------------------------------------------------------------------------
__global__ __launch_bounds__(256, 4) void k_gemm_big(
    const float* __restrict__ Y,
    const float* __restrict__ W,
    float* __restrict__ Yp) {
  __shared__ short8 lwr[2048];  // 32 KB swizzled bf16 W
  stage_w(W, lwr);
  const int wid  = threadIdx.x >> 6;
  const int lane = threadIdx.x & 63;
  const int l15  = lane & 15;
  const int lg   = lane >> 4;
  const int koff = lg * 8;

#pragma unroll 1
  for (int ch = 0; ch < 2; ++ch) {
    const int ebase = (blockIdx.x * 2 + ch) * 128 + wid * 32;

    short8 a[2][4];
#pragma unroll
    for (int mt = 0; mt < 2; ++mt) {
      const float* yr = Y + (size_t)(ebase + mt * 16 + l15) * DD;
#pragma unroll
      for (int kk = 0; kk < 4; ++kk) {
        const f32x4* p = (const f32x4*)(yr + kk * 32 + koff);
        f32x4 v0 = __builtin_nontemporal_load(p);
        f32x4 v1 = __builtin_nontemporal_load(p + 1);
        short8 av;
        unsigned* au = (unsigned*)&av;
        au[0] = pack_bf2(v0[0], v0[1]);
        au[1] = pack_bf2(v0[2], v0[3]);
        au[2] = pack_bf2(v1[0], v1[1]);
        au[3] = pack_bf2(v1[2], v1[3]);
        a[mt][kk] = av;
      }
    }

    f32x4 acc[2][8];
#pragma unroll
    for (int mt = 0; mt < 2; ++mt)
#pragma unroll
      for (int nt = 0; nt < 8; ++nt)
        acc[mt][nt] = (f32x4){0.f, 0.f, 0.f, 0.f};

#pragma unroll
    for (int nt = 0; nt < 8; ++nt) {
      const int j = nt * 16 + l15;
#pragma unroll
      for (int kk = 0; kk < 4; ++kk) {
        const int kc = kk * 4 + lg;
        short8 b = lwr[(j << 4) | (kc ^ (j & 7))];
        acc[0][nt] = __builtin_amdgcn_mfma_f32_16x16x32_bf16(a[0][kk], b, acc[0][nt], 0, 0, 0);
        acc[1][nt] = __builtin_amdgcn_mfma_f32_16x16x32_bf16(a[1][kk], b, acc[1][nt], 0, 0, 0);
      }
    }

    // C layout: col = lane&15, row = (lane>>4)*4 + reg
    const int r0 = lg * 4;
#pragma unroll
    for (int mt = 0; mt < 2; ++mt) {
#pragma unroll
      for (int reg = 0; reg < 4; ++reg) {
        float* orow = Yp + (size_t)(ebase + mt * 16 + r0 + reg) * DD + l15;
#pragma unroll
        for (int nt = 0; nt < 8; ++nt)
          orow[nt * 16] = acc[mt][nt][reg];
      }
    }
  }
}

// ---------------------------------------------------------------------------
// Gather + epilogue: X'[n] = relu(X[n] + sum_{e in CSR[n]} Yp[e])
// one wave per node; lane covers cols 2*lane, 2*lane+1 (512B coalesced rows)
// ---------------------------------------------------------------------------
__global__ __launch_bounds__(256) void k_gather(
    const float* __restrict__ Yp,
    const int* __restrict__ rowptr,
    const int* __restrict__ col,
    const float* __restrict__ X,
    float* __restrict__ Xp) {
  const int node = blockIdx.x * 4 + (threadIdx.x >> 6);
  const int lane = threadIdx.x & 63;
  const size_t co = 2 * lane;
  const int b  = rowptr[node];
  const int en = rowptr[node + 1];

  f32x2 acc = *(const f32x2*)(X + (size_t)node * DD + co);
  int i = b;
  for (; i + 8 <= en; i += 8) {
    f32x2 v0 = *(const f32x2*)(Yp + (size_t)col[i]     * DD + co);
    f32x2 v1 = *(const f32x2*)(Yp + (size_t)col[i + 1] * DD + co);
    f32x2 v2 = *(const f32x2*)(Yp + (size_t)col[i + 2] * DD + co);
    f32x2 v3 = *(const f32x2*)(Yp + (size_t)col[i + 3] * DD + co);
    f32x2 v4 = *(const f32x2*)(Yp + (size_t)col[i + 4] * DD + co);
    f32x2 v5 = *(const f32x2*)(Yp + (size_t)col[i + 5] * DD + co);
    f32x2 v6 = *(const f32x2*)(Yp + (size_t)col[i + 6] * DD + co);
    f32x2 v7 = *(const f32x2*)(Yp + (size_t)col[i + 7] * DD + co);
    acc += v0; acc += v1; acc += v2; acc += v3;
    acc += v4; acc += v5; acc += v6; acc += v7;
  }
  for (; i < en; ++i) {
    acc += *(const f32x2*)(Yp + (size_t)col[i] * DD + co);
  }
  f32x2 r;
  r[0] = acc[0] > 0.f ? acc[0] : 0.f;
  r[1] = acc[1] > 0.f ? acc[1] : 0.f;
  *(f32x2*)(Xp + (size_t)node * DD + co) = r;
}

extern "C" void kernel_launch(void* const* d_in, const int* in_sizes, int n_in,
                              void* d_out, int out_size, void* d_ws, size_t ws_size,
                              hipStream_t stream) {
  const float* X  = (const float*)d_in[0];
  const float* Y  = (const float*)d_in[1];
  const float* W  = (const float*)d_in[2];
  const int*   EI = (const int*)d_in[3];

  float* Xp = (float*)d_out;
  float* Yp = Xp + (size_t)N_NODES * DD;   // outputs concatenated: X' then Y'

  int* w      = (int*)d_ws;
  int* count  = w;                // 10000
  int* rowptr = w + 10000;        // 10001
  int* cursor = w + 20001;        // 10000
  int* col    = w + 30001;        // 640000   (total ~2.68 MB of ws)

  k_zero<<<(N_NODES + 255) / 256, 256, 0, stream>>>(count);
  k_hist<<<N_EDGES / 256, 256, 0, stream>>>(EI, count);
  k_scan<<<1, 1024, 0, stream>>>(count, rowptr, cursor);
  k_fill<<<N_EDGES / 256, 256, 0, stream>>>(EI, cursor, col);
  k_gemm_big<<<2500, 256, 0, stream>>>(Y, W, Yp);
  k_gather<<<2500, 256, 0, stream>>>(Yp, rowptr, col, X, Xp);
}

// Round 5
// 395.749 us; speedup vs baseline: 1.1701x; 1.1701x over previous
//
#include <hip/hip_runtime.h>

#define N_NODES 10000
#define N_EDGES 640000
#define DD 128

typedef __attribute__((ext_vector_type(8))) short short8;
typedef __attribute__((ext_vector_type(8))) float f32x8;
typedef __attribute__((ext_vector_type(4))) float f32x4;
typedef __attribute__((ext_vector_type(2))) float f32x2;

// pack two fp32 -> (bf16(hi)<<16)|bf16(lo), truncating: one v_perm_b32
__device__ __forceinline__ unsigned pack_bf2(float lo, float hi) {
  return __builtin_amdgcn_perm(__float_as_uint(hi), __float_as_uint(lo), 0x07060302u);
}

// Stage W (128x128 fp32 row-major) into LDS as bf16 with per-row XOR swizzle
// on 16B chunks: chunk c (cols c*8..c*8+7) of row j at slot (j*16)|(c^(j&7)).
__device__ __forceinline__ void stage_w(const float* __restrict__ W,
                                        short8* lwr) {
  const int tid = threadIdx.x;
#pragma unroll
  for (int t = 0; t < 8; ++t) {
    int s = t * 256 + tid;                          // chunk id 0..2047
    f32x8 v = *(const f32x8*)(W + (size_t)s * 8);   // coalesced 32B cached
    short8 av;
    unsigned* au = (unsigned*)&av;
    au[0] = pack_bf2(v[0], v[1]);
    au[1] = pack_bf2(v[2], v[3]);
    au[2] = pack_bf2(v[4], v[5]);
    au[3] = pack_bf2(v[6], v[7]);
    int j = s >> 4;
    int c = s & 15;
    lwr[(j << 4) | (c ^ (j & 7))] = av;
  }
  __syncthreads();
}

// ---------------------------------------------------------------------------
// CSR build: zero -> histogram -> scan -> fill
// ---------------------------------------------------------------------------
__global__ __launch_bounds__(256) void k_zero(int* __restrict__ count) {
  const int i = blockIdx.x * 256 + threadIdx.x;
  if (i < N_NODES) count[i] = 0;
}

__global__ __launch_bounds__(256) void k_hist(const int* __restrict__ EI,
                                              int* __restrict__ count) {
  const int e = blockIdx.x * 256 + threadIdx.x;
  atomicAdd(&count[EI[2 * e]], 1);
}

__global__ __launch_bounds__(1024) void k_scan(const int* __restrict__ count,
                                               int* __restrict__ rowptr,
                                               int* __restrict__ cursor) {
  __shared__ int part[1024];
  const int tid = threadIdx.x;
  const int base = tid * 10;
  int local[10];
  int s = 0;
#pragma unroll
  for (int i = 0; i < 10; ++i) {
    const int idx = base + i;
    const int v = (idx < N_NODES) ? count[idx] : 0;
    local[i] = s;
    s += v;
  }
  part[tid] = s;
  __syncthreads();
  for (int off = 1; off < 1024; off <<= 1) {
    int v = 0;
    if (tid >= off) v = part[tid - off];
    __syncthreads();
    if (tid >= off) part[tid] += v;
    __syncthreads();
  }
  const int excl = (tid > 0) ? part[tid - 1] : 0;
#pragma unroll
  for (int i = 0; i < 10; ++i) {
    const int idx = base + i;
    if (idx < N_NODES) {
      const int r = excl + local[i];
      rowptr[idx] = r;
      cursor[idx] = r;
    }
  }
  if (tid == 1023) rowptr[N_NODES] = part[1023];
}

__global__ __launch_bounds__(256) void k_fill(const int* __restrict__ EI,
                                              int* __restrict__ cursor,
                                              int* __restrict__ col) {
  const int e = blockIdx.x * 256 + threadIdx.x;
  const int s = EI[2 * e];
  const int pos = atomicAdd(&cursor[s], 1);
  col[pos] = e;
}

// ---------------------------------------------------------------------------
// Big GEMM: Yp = Y @ W^T   (640000x128 @ 128x128), fp32 I/O, bf16 MFMA
// One 128-edge chunk per block; per wave 32 edges (2 x 16-row MFMA tiles).
// Epilogue: acc is transposed through the (dead) W LDS buffer so every
// global store is a 1KB-contiguous dwordx4 per wave (no partial-line RMW).
// ---------------------------------------------------------------------------
__global__ __launch_bounds__(256, 2) void k_gemm_big(
    const float* __restrict__ Y,
    const float* __restrict__ W,
    float* __restrict__ Yp) {
  __shared__ float smem[8192];          // 32 KB, dual-purpose
  short8* lwr = (short8*)smem;
  stage_w(W, lwr);
  const int wid  = threadIdx.x >> 6;
  const int lane = threadIdx.x & 63;
  const int l15  = lane & 15;
  const int lg   = lane >> 4;
  const int koff = lg * 8;
  const int ebase = blockIdx.x * 128 + wid * 32;

  // A fragments: lane holds Y[row][kk*32+koff .. +7], row = ebase+mt*16+l15
  short8 a[2][4];
#pragma unroll
  for (int mt = 0; mt < 2; ++mt) {
    const float* yr = Y + (size_t)(ebase + mt * 16 + l15) * DD;
#pragma unroll
    for (int kk = 0; kk < 4; ++kk) {
      f32x8 v = *(const f32x8*)(yr + kk * 32 + koff);
      short8 av;
      unsigned* au = (unsigned*)&av;
      au[0] = pack_bf2(v[0], v[1]);
      au[1] = pack_bf2(v[2], v[3]);
      au[2] = pack_bf2(v[4], v[5]);
      au[3] = pack_bf2(v[6], v[7]);
      a[mt][kk] = av;
    }
  }

  f32x4 acc[2][8];
#pragma unroll
  for (int mt = 0; mt < 2; ++mt)
#pragma unroll
    for (int nt = 0; nt < 8; ++nt)
      acc[mt][nt] = (f32x4){0.f, 0.f, 0.f, 0.f};

#pragma unroll
  for (int nt = 0; nt < 8; ++nt) {
    const int j = nt * 16 + l15;                    // W row = output col
#pragma unroll
    for (int kk = 0; kk < 4; ++kk) {
      const int kc = kk * 4 + lg;
      short8 b = lwr[(j << 4) | (kc ^ (j & 7))];
      acc[0][nt] = __builtin_amdgcn_mfma_f32_16x16x32_bf16(a[0][kk], b, acc[0][nt], 0, 0, 0);
      acc[1][nt] = __builtin_amdgcn_mfma_f32_16x16x32_bf16(a[1][kk], b, acc[1][nt], 0, 0, 0);
    }
  }

  __syncthreads();                      // all waves done reading W: reuse LDS
  float* cb = smem + wid * 2048;        // per-wave 16x128 f32 tile (8 KB)
  const int r0 = lg * 4;

#pragma unroll 1
  for (int mt = 0; mt < 2; ++mt) {
    // scatter acc into LDS; swizzle: phys_col = col ^ (bit2(row)<<4)
    // (row = lg*4+reg -> bit2(row) = lg&1), 2 lanes/bank on every write.
#pragma unroll
    for (int nt = 0; nt < 8; ++nt) {
#pragma unroll
      for (int reg = 0; reg < 4; ++reg) {
        const int pc = (nt * 16 + l15) ^ ((lg & 1) << 4);
        cb[(r0 + reg) * 128 + pc] = acc[mt][nt][reg];
      }
    }
    __syncthreads();
    // read back rows, store 1KB-contiguous per instruction
#pragma unroll
    for (int t = 0; t < 8; ++t) {
      const int row   = (lane >> 5) + t * 2;
      const int cbase = (lane & 31) * 4;
      const int pc    = cbase ^ (((row >> 2) & 1) << 4);
      f32x4 v = *(const f32x4*)&cb[row * 128 + pc];
      *(f32x4*)(Yp + (size_t)(ebase + mt * 16 + row) * DD + cbase) = v;
    }
    __syncthreads();
  }
}

// ---------------------------------------------------------------------------
// Gather + epilogue: X'[n] = relu(X[n] + sum_{e in CSR[n]} Yp[e])
// one wave per node; lane covers cols 2*lane, 2*lane+1 (512B coalesced rows)
// ---------------------------------------------------------------------------
__global__ __launch_bounds__(256) void k_gather(
    const float* __restrict__ Yp,
    const int* __restrict__ rowptr,
    const int* __restrict__ col,
    const float* __restrict__ X,
    float* __restrict__ Xp) {
  const int node = blockIdx.x * 4 + (threadIdx.x >> 6);
  const int lane = threadIdx.x & 63;
  const size_t co = 2 * lane;
  const int b  = rowptr[node];
  const int en = rowptr[node + 1];

  f32x2 acc = *(const f32x2*)(X + (size_t)node * DD + co);
  int i = b;
  for (; i + 8 <= en; i += 8) {
    f32x2 v0 = *(const f32x2*)(Yp + (size_t)col[i]     * DD + co);
    f32x2 v1 = *(const f32x2*)(Yp + (size_t)col[i + 1] * DD + co);
    f32x2 v2 = *(const f32x2*)(Yp + (size_t)col[i + 2] * DD + co);
    f32x2 v3 = *(const f32x2*)(Yp + (size_t)col[i + 3] * DD + co);
    f32x2 v4 = *(const f32x2*)(Yp + (size_t)col[i + 4] * DD + co);
    f32x2 v5 = *(const f32x2*)(Yp + (size_t)col[i + 5] * DD + co);
    f32x2 v6 = *(const f32x2*)(Yp + (size_t)col[i + 6] * DD + co);
    f32x2 v7 = *(const f32x2*)(Yp + (size_t)col[i + 7] * DD + co);
    acc += v0; acc += v1; acc += v2; acc += v3;
    acc += v4; acc += v5; acc += v6; acc += v7;
  }
  for (; i < en; ++i) {
    acc += *(const f32x2*)(Yp + (size_t)col[i] * DD + co);
  }
  f32x2 r;
  r[0] = acc[0] > 0.f ? acc[0] : 0.f;
  r[1] = acc[1] > 0.f ? acc[1] : 0.f;
  *(f32x2*)(Xp + (size_t)node * DD + co) = r;
}

extern "C" void kernel_launch(void* const* d_in, const int* in_sizes, int n_in,
                              void* d_out, int out_size, void* d_ws, size_t ws_size,
                              hipStream_t stream) {
  const float* X  = (const float*)d_in[0];
  const float* Y  = (const float*)d_in[1];
  const float* W  = (const float*)d_in[2];
  const int*   EI = (const int*)d_in[3];

  float* Xp = (float*)d_out;
  float* Yp = Xp + (size_t)N_NODES * DD;   // outputs concatenated: X' then Y'

  int* w      = (int*)d_ws;
  int* count  = w;                // 10000
  int* rowptr = w + 10000;        // 10001
  int* cursor = w + 20001;        // 10000
  int* col    = w + 30001;        // 640000   (total ~2.68 MB of ws)

  k_zero<<<(N_NODES + 255) / 256, 256, 0, stream>>>(count);
  k_hist<<<N_EDGES / 256, 256, 0, stream>>>(EI, count);
  k_scan<<<1, 1024, 0, stream>>>(count, rowptr, cursor);
  k_fill<<<N_EDGES / 256, 256, 0, stream>>>(EI, cursor, col);
  k_gemm_big<<<N_EDGES / 128, 256, 0, stream>>>(Y, W, Yp);
  k_gather<<<N_NODES / 4, 256, 0, stream>>>(Yp, rowptr, col, X, Xp);
}

// Round 6
// 314.707 us; speedup vs baseline: 1.4714x; 1.2575x over previous
//
#include <hip/hip_runtime.h>

#define N_NODES 10000
#define N_EDGES 640000
#define DD 128

typedef __attribute__((ext_vector_type(8))) short short8;
typedef __attribute__((ext_vector_type(8))) float f32x8;
typedef __attribute__((ext_vector_type(4))) float f32x4;
typedef __attribute__((ext_vector_type(2))) float f32x2;

// pack two fp32 -> (bf16(hi)<<16)|bf16(lo), truncating: one v_perm_b32
__device__ __forceinline__ unsigned pack_bf2(float lo, float hi) {
  return __builtin_amdgcn_perm(__float_as_uint(hi), __float_as_uint(lo), 0x07060302u);
}

// Stage W (128x128 fp32 row-major) into LDS as bf16 with per-row XOR swizzle
// on 16B chunks: chunk c (cols c*8..c*8+7) of row j at slot (j*16)|(c^(j&7)).
__device__ __forceinline__ void stage_w(const float* __restrict__ W,
                                        short8* lwr) {
  const int tid = threadIdx.x;
#pragma unroll
  for (int t = 0; t < 8; ++t) {
    int s = t * 256 + tid;                          // chunk id 0..2047
    f32x8 v = *(const f32x8*)(W + (size_t)s * 8);   // coalesced 32B cached
    short8 av;
    unsigned* au = (unsigned*)&av;
    au[0] = pack_bf2(v[0], v[1]);
    au[1] = pack_bf2(v[2], v[3]);
    au[2] = pack_bf2(v[4], v[5]);
    au[3] = pack_bf2(v[6], v[7]);
    int j = s >> 4;
    int c = s & 15;
    lwr[(j << 4) | (c ^ (j & 7))] = av;
  }
  __syncthreads();
}

// ---------------------------------------------------------------------------
// CSR build: zero -> histogram -> scan -> fill
// ---------------------------------------------------------------------------
__global__ __launch_bounds__(256) void k_zero(int* __restrict__ count) {
  const int i = blockIdx.x * 256 + threadIdx.x;
  if (i < N_NODES) count[i] = 0;
}

__global__ __launch_bounds__(256) void k_hist(const int* __restrict__ EI,
                                              int* __restrict__ count) {
  const int e = blockIdx.x * 256 + threadIdx.x;
  atomicAdd(&count[EI[2 * e]], 1);
}

__global__ __launch_bounds__(1024) void k_scan(const int* __restrict__ count,
                                               int* __restrict__ rowptr,
                                               int* __restrict__ cursor) {
  __shared__ int part[1024];
  const int tid = threadIdx.x;
  const int base = tid * 10;
  int local[10];
  int s = 0;
#pragma unroll
  for (int i = 0; i < 10; ++i) {
    const int idx = base + i;
    const int v = (idx < N_NODES) ? count[idx] : 0;
    local[i] = s;
    s += v;
  }
  part[tid] = s;
  __syncthreads();
  for (int off = 1; off < 1024; off <<= 1) {
    int v = 0;
    if (tid >= off) v = part[tid - off];
    __syncthreads();
    if (tid >= off) part[tid] += v;
    __syncthreads();
  }
  const int excl = (tid > 0) ? part[tid - 1] : 0;
#pragma unroll
  for (int i = 0; i < 10; ++i) {
    const int idx = base + i;
    if (idx < N_NODES) {
      const int r = excl + local[i];
      rowptr[idx] = r;
      cursor[idx] = r;
    }
  }
  if (tid == 1023) rowptr[N_NODES] = part[1023];
}

__global__ __launch_bounds__(256) void k_fill(const int* __restrict__ EI,
                                              int* __restrict__ cursor,
                                              int* __restrict__ col) {
  const int e = blockIdx.x * 256 + threadIdx.x;
  const int s = EI[2 * e];
  const int pos = atomicAdd(&cursor[s], 1);
  col[pos] = e;
}

// ---------------------------------------------------------------------------
// Big GEMM: Yp = Y @ W^T   (640000x128 @ 128x128), fp32 I/O, bf16 MFMA
// SWAPPED operands: D = mfma(W_frag, Y_frag) so each lane's f32x4 acc is 4
// consecutive Yp columns of one row -> direct contiguous dwordx4 NT stores
// (16 rows x 64B full lines per instruction). No LDS transpose, no epilogue
// syncs. Yp is never re-read (gather now sums raw Y), so NT is safe.
// ---------------------------------------------------------------------------
__global__ __launch_bounds__(256, 2) void k_gemm_big(
    const float* __restrict__ Y,
    const float* __restrict__ W,
    float* __restrict__ Yp) {
  __shared__ short8 lwr[2048];   // 32 KB swizzled bf16 W
  stage_w(W, lwr);
  const int wid  = threadIdx.x >> 6;
  const int lane = threadIdx.x & 63;
  const int l15  = lane & 15;
  const int lg   = lane >> 4;
  const int koff = lg * 8;
  const int ebase = blockIdx.x * 128 + wid * 32;

  // Y fragments: lane holds Y[row][kk*32+koff .. +7], row = ebase+mt*16+l15
  short8 a[2][4];
#pragma unroll
  for (int mt = 0; mt < 2; ++mt) {
    const float* yr = Y + (size_t)(ebase + mt * 16 + l15) * DD;
#pragma unroll
    for (int kk = 0; kk < 4; ++kk) {
      f32x8 v = *(const f32x8*)(yr + kk * 32 + koff);
      short8 av;
      unsigned* au = (unsigned*)&av;
      au[0] = pack_bf2(v[0], v[1]);
      au[1] = pack_bf2(v[2], v[3]);
      au[2] = pack_bf2(v[4], v[5]);
      au[3] = pack_bf2(v[6], v[7]);
      a[mt][kk] = av;
    }
  }

  f32x4 acc[2][8];
#pragma unroll
  for (int mt = 0; mt < 2; ++mt)
#pragma unroll
    for (int nt = 0; nt < 8; ++nt)
      acc[mt][nt] = (f32x4){0.f, 0.f, 0.f, 0.f};

#pragma unroll
  for (int nt = 0; nt < 8; ++nt) {
    const int j = nt * 16 + l15;                    // W row (= output col blk)
#pragma unroll
    for (int kk = 0; kk < 4; ++kk) {
      const int kc = kk * 4 + lg;
      short8 b = lwr[(j << 4) | (kc ^ (j & 7))];
      // D[i][j] = W_i . Y_j : lane holds Yp[row=mt*16+l15][nt*16+lg*4+reg]
      acc[0][nt] = __builtin_amdgcn_mfma_f32_16x16x32_bf16(b, a[0][kk], acc[0][nt], 0, 0, 0);
      acc[1][nt] = __builtin_amdgcn_mfma_f32_16x16x32_bf16(b, a[1][kk], acc[1][nt], 0, 0, 0);
    }
  }

#pragma unroll
  for (int mt = 0; mt < 2; ++mt) {
    float* orow = Yp + (size_t)(ebase + mt * 16 + l15) * DD + lg * 4;
#pragma unroll
    for (int nt = 0; nt < 8; ++nt)
      __builtin_nontemporal_store(acc[mt][nt], (f32x4*)(orow + nt * 16));
  }
}

// ---------------------------------------------------------------------------
// Gather raw Y rows (CSR order): segY[n] = sum_{e in CSR[n]} Y[e]  (fp32)
// one wave per node; lane covers cols 2*lane, 2*lane+1. Y is L3-warm from
// the GEMM's cached reads.
// ---------------------------------------------------------------------------
__global__ __launch_bounds__(256) void k_gather_y(
    const float* __restrict__ Y,
    const int* __restrict__ rowptr,
    const int* __restrict__ col,
    float* __restrict__ segY) {
  const int node = blockIdx.x * 4 + (threadIdx.x >> 6);
  const int lane = threadIdx.x & 63;
  const size_t co = 2 * lane;
  const int b  = rowptr[node];
  const int en = rowptr[node + 1];

  f32x2 acc = (f32x2){0.f, 0.f};
  int i = b;
  for (; i + 8 <= en; i += 8) {
    f32x2 v0 = *(const f32x2*)(Y + (size_t)col[i]     * DD + co);
    f32x2 v1 = *(const f32x2*)(Y + (size_t)col[i + 1] * DD + co);
    f32x2 v2 = *(const f32x2*)(Y + (size_t)col[i + 2] * DD + co);
    f32x2 v3 = *(const f32x2*)(Y + (size_t)col[i + 3] * DD + co);
    f32x2 v4 = *(const f32x2*)(Y + (size_t)col[i + 4] * DD + co);
    f32x2 v5 = *(const f32x2*)(Y + (size_t)col[i + 5] * DD + co);
    f32x2 v6 = *(const f32x2*)(Y + (size_t)col[i + 6] * DD + co);
    f32x2 v7 = *(const f32x2*)(Y + (size_t)col[i + 7] * DD + co);
    acc += v0; acc += v1; acc += v2; acc += v3;
    acc += v4; acc += v5; acc += v6; acc += v7;
  }
  for (; i < en; ++i) {
    acc += *(const f32x2*)(Y + (size_t)col[i] * DD + co);
  }
  *(f32x2*)(segY + (size_t)node * DD + co) = acc;
}

// ---------------------------------------------------------------------------
// Small GEMM + epilogue: X' = relu(X + segY @ W^T)  (10000x128, fp32 I/O)
// Swapped operands like k_gemm_big -> contiguous f32x4 stores + X loads.
// ---------------------------------------------------------------------------
__global__ __launch_bounds__(256, 2) void k_small(
    const float* __restrict__ segY,
    const float* __restrict__ W,
    const float* __restrict__ X,
    float* __restrict__ Xp) {
  __shared__ short8 lwr[2048];
  stage_w(W, lwr);
  const int wid  = threadIdx.x >> 6;
  const int lane = threadIdx.x & 63;
  const int l15  = lane & 15;
  const int lg   = lane >> 4;
  const int koff = lg * 8;
  const int rbase = blockIdx.x * 128 + wid * 32;

  short8 a[2][4];
#pragma unroll
  for (int mt = 0; mt < 2; ++mt) {
    int row = rbase + mt * 16 + l15;
    if (row > N_NODES - 1) row = N_NODES - 1;   // clamp (stores guarded)
    const float* sr = segY + (size_t)row * DD + koff;
#pragma unroll
    for (int kk = 0; kk < 4; ++kk) {
      f32x8 v = *(const f32x8*)(sr + kk * 32);
      short8 av;
      unsigned* au = (unsigned*)&av;
      au[0] = pack_bf2(v[0], v[1]);
      au[1] = pack_bf2(v[2], v[3]);
      au[2] = pack_bf2(v[4], v[5]);
      au[3] = pack_bf2(v[6], v[7]);
      a[mt][kk] = av;
    }
  }

  f32x4 acc[2][8];
#pragma unroll
  for (int mt = 0; mt < 2; ++mt)
#pragma unroll
    for (int nt = 0; nt < 8; ++nt)
      acc[mt][nt] = (f32x4){0.f, 0.f, 0.f, 0.f};

#pragma unroll
  for (int nt = 0; nt < 8; ++nt) {
    const int j = nt * 16 + l15;
#pragma unroll
    for (int kk = 0; kk < 4; ++kk) {
      const int kc = kk * 4 + lg;
      short8 b = lwr[(j << 4) | (kc ^ (j & 7))];
      acc[0][nt] = __builtin_amdgcn_mfma_f32_16x16x32_bf16(b, a[0][kk], acc[0][nt], 0, 0, 0);
      acc[1][nt] = __builtin_amdgcn_mfma_f32_16x16x32_bf16(b, a[1][kk], acc[1][nt], 0, 0, 0);
    }
  }

#pragma unroll
  for (int mt = 0; mt < 2; ++mt) {
    const int row = rbase + mt * 16 + l15;
    if (row < N_NODES) {
      const float* xr = X  + (size_t)row * DD + lg * 4;
      float*       orow = Xp + (size_t)row * DD + lg * 4;
#pragma unroll
      for (int nt = 0; nt < 8; ++nt) {
        f32x4 x = *(const f32x4*)(xr + nt * 16);
        f32x4 v = acc[mt][nt] + x;
        f32x4 r;
        r[0] = v[0] > 0.f ? v[0] : 0.f;
        r[1] = v[1] > 0.f ? v[1] : 0.f;
        r[2] = v[2] > 0.f ? v[2] : 0.f;
        r[3] = v[3] > 0.f ? v[3] : 0.f;
        *(f32x4*)(orow + nt * 16) = r;
      }
    }
  }
}

extern "C" void kernel_launch(void* const* d_in, const int* in_sizes, int n_in,
                              void* d_out, int out_size, void* d_ws, size_t ws_size,
                              hipStream_t stream) {
  const float* X  = (const float*)d_in[0];
  const float* Y  = (const float*)d_in[1];
  const float* W  = (const float*)d_in[2];
  const int*   EI = (const int*)d_in[3];

  float* Xp = (float*)d_out;
  float* Yp = Xp + (size_t)N_NODES * DD;   // outputs concatenated: X' then Y'

  int* w      = (int*)d_ws;
  int* count  = w;                // 10000
  int* rowptr = w + 10000;        // 10001
  int* cursor = w + 20001;        // 10000
  int* col    = w + 30001;        // 640000
  float* segY = (float*)(w + 670001 + 15);  // 10000*128 fp32 = 5.12 MB

  k_zero<<<(N_NODES + 255) / 256, 256, 0, stream>>>(count);
  k_hist<<<N_EDGES / 256, 256, 0, stream>>>(EI, count);
  k_scan<<<1, 1024, 0, stream>>>(count, rowptr, cursor);
  k_fill<<<N_EDGES / 256, 256, 0, stream>>>(EI, cursor, col);
  k_gemm_big<<<N_EDGES / 128, 256, 0, stream>>>(Y, W, Yp);
  k_gather_y<<<N_NODES / 4, 256, 0, stream>>>(Y, rowptr, col, segY);
  k_small<<<(N_NODES + 127) / 128, 256, 0, stream>>>(segY, W, X, Xp);
}